// Round 9
// baseline (3176.742 us; speedup 1.0000x reference)
//
#include <hip/hip_runtime.h>
#include <stdint.h>

// Problem sizes (fixed)
#define B_ 32
#define T_ 128
#define L_ 64
#define H_ 512
#define A_ 256
#define NB 32   // cooperative blocks; block k owns h-dims [16k,16k+16)

typedef short short8 __attribute__((ext_vector_type(8)));
typedef float floatx4 __attribute__((ext_vector_type(4)));

__device__ __forceinline__ float b2f(unsigned short u) {
  union { unsigned int i; float f; } x; x.i = ((unsigned int)u) << 16; return x.f;
}
__device__ __forceinline__ unsigned short f2b(float f) {
  union { float f; unsigned int i; } x; x.f = f;
  unsigned int i = x.i;
  unsigned int r = (i + 0x7fffu + ((i >> 16) & 1u)) >> 16;  // RNE
  return (unsigned short)r;
}
__device__ __forceinline__ void unpack2(unsigned int p, float& lo, float& hi) {
  union { unsigned int i; float f; } a, b;
  a.i = p << 16; b.i = p & 0xffff0000u;
  lo = a.f; hi = b.f;
}
__device__ __forceinline__ float tanh_fast(float x) {
  float e = __expf(2.f * x);
  return 1.f - 2.f / (e + 1.f);
}
__device__ __forceinline__ float sigmoid_fast(float x) {
  return 1.f / (1.f + __expf(-x));
}
template<bool F32>
__device__ __forceinline__ float ld1(const void* p, size_t i) {
  if (F32) return ((const float*)p)[i];
  return b2f(((const unsigned short*)p)[i]);
}
template<bool F32>
__device__ __forceinline__ void ld8(const void* p, size_t i, float* f) {
  if (F32) {
    const float4 a = *(const float4*)((const float*)p + i);
    const float4 b = *(const float4*)((const float*)p + i + 4);
    f[0] = a.x; f[1] = a.y; f[2] = a.z; f[3] = a.w;
    f[4] = b.x; f[5] = b.y; f[6] = b.z; f[7] = b.w;
  } else {
    const uint4 v = *(const uint4*)((const unsigned short*)p + i);
    unpack2(v.x, f[0], f[1]); unpack2(v.y, f[2], f[3]);
    unpack2(v.z, f[4], f[5]); unpack2(v.w, f[6], f[7]);
  }
}

// ---------------------------------------------------------------------------
// Fused fp32->bf16 convert for X | Ctx | attW1c | W0..W3.  4 elem/thread.
// ---------------------------------------------------------------------------
__global__ __launch_bounds__(256) void conv_all(
    const float* __restrict__ X, const float* __restrict__ Ctx,
    const float* __restrict__ W1c,
    const float* __restrict__ W0, const float* __restrict__ W1,
    const float* __restrict__ W2, const float* __restrict__ W3,
    unsigned short* __restrict__ Xbf, unsigned short* __restrict__ cxb,
    unsigned short* __restrict__ w1cb, unsigned short* __restrict__ Wb4)
{
  const size_t i = ((size_t)blockIdx.x * 256 + threadIdx.x) * 4;
  const float* src; unsigned short* dst; size_t off;
  if (i < 2097152) { src = X; dst = Xbf; off = i; }
  else if (i < 3145728) { src = Ctx; dst = cxb; off = i - 2097152; }
  else if (i < 3276800) { src = W1c; dst = w1cb; off = i - 3145728; }
  else {
    const size_t j = i - 3276800;
    const int g = (int)(j >> 18);
    src = (g == 0) ? W0 : (g == 1) ? W1 : (g == 2) ? W2 : W3;
    dst = Wb4 + ((size_t)g << 18);
    off = j & 262143;
  }
  const float4 v = *(const float4*)(src + off);
  ushort4 o;
  o.x = f2b(v.x); o.y = f2b(v.y); o.z = f2b(v.z); o.w = f2b(v.w);
  *(ushort4*)(dst + off) = o;
}

// ---------------------------------------------------------------------------
// cxbT[b][d][l] = bf16(Ctx[b][l][d]).  grid (32, 8) x 256.
// ---------------------------------------------------------------------------
__global__ __launch_bounds__(256) void transpose_cxbT(
    const float* __restrict__ Ctx, unsigned short* __restrict__ cxbT)
{
  const int b = blockIdx.x, dg = blockIdx.y;
  const int d = dg * 64 + (threadIdx.x >> 2), lg = threadIdx.x & 3;
  unsigned short tmp[16];
#pragma unroll
  for (int i = 0; i < 16; ++i)
    tmp[i] = f2b(Ctx[((size_t)b * 64 + lg * 16 + i) * 512 + d]);
  unsigned short* dst = cxbT + ((size_t)b * 512 + d) * 64 + lg * 16;
  *(uint4*)dst = *(const uint4*)&tmp[0];
  *(uint4*)(dst + 8) = *(const uint4*)&tmp[8];
}

// ---------------------------------------------------------------------------
// MFMA bf16 GEMM (mode 0): out[row*ldo + co + col] = A[M,512]@W[512,N] + bias.
// ---------------------------------------------------------------------------
__global__ __launch_bounds__(256) void gemm_bias(
    const unsigned short* __restrict__ A,
    const unsigned short* __restrict__ W,
    const float* __restrict__ bias,
    unsigned short* __restrict__ out,
    int M, int N, int ldo, int co)
{
  const int K = 512;
  __shared__ __attribute__((aligned(16))) unsigned short As[16 * 32];
  __shared__ __attribute__((aligned(16))) unsigned short Bs[32 * 64];
  const int tid = threadIdx.x;
  const int m0 = blockIdx.y * 16;
  const int n0 = blockIdx.x * 64;
  const int lane = tid & 63;
  const int w = tid >> 6;
  const int mfrag = lane & 15;
  const int q = lane >> 4;
  floatx4 acc = {0.f, 0.f, 0.f, 0.f};
  for (int k0 = 0; k0 < K; k0 += 32) {
    if (tid < 64) {
      const int r = tid >> 2, cg = tid & 3;
      *(uint4*)&As[r * 32 + cg * 8] =
          *(const uint4*)(A + (size_t)(m0 + r) * K + k0 + cg * 8);
    }
    {
      const int r = tid >> 3, cg = tid & 7;
      *(uint4*)&Bs[r * 64 + cg * 8] =
          *(const uint4*)(W + (size_t)(k0 + r) * N + n0 + cg * 8);
    }
    __syncthreads();
    const short8 af = *(const short8*)&As[mfrag * 32 + q * 8];
    short8 bf;
    const int wn = w * 16 + mfrag;
#pragma unroll
    for (int j = 0; j < 8; ++j) bf[j] = (short)Bs[(q * 8 + j) * 64 + wn];
    acc = __builtin_amdgcn_mfma_f32_16x16x32_bf16(af, bf, acc, 0, 0, 0);
    __syncthreads();
  }
  const int col = n0 + w * 16 + mfrag;
  const float bv = bias ? bias[col] : 0.f;
#pragma unroll
  for (int i = 0; i < 4; ++i)
    out[(size_t)(m0 + q * 4 + i) * ldo + co + col] = f2b(acc[i] + bv);
}

// ---------------------------------------------------------------------------
// xg GEMM, z = gate.  out layout [t][2048 col][32 b] (batch-minor).
// ---------------------------------------------------------------------------
struct GB4 { const float* b0; const float* b1; const float* b2; const float* b3; };

__global__ __launch_bounds__(256) void gemm_xg(
    const unsigned short* __restrict__ A,      // Xbf [4096,512]
    const unsigned short* __restrict__ Wb4,    // [4][512][512]
    GB4 gb, unsigned short* __restrict__ out)
{
  const int K = 512, N = 512;
  const int g = blockIdx.z;
  const unsigned short* W = Wb4 + ((size_t)g << 18);
  const float* bias = (g == 0) ? gb.b0 : (g == 1) ? gb.b1 : (g == 2) ? gb.b2 : gb.b3;
  __shared__ __attribute__((aligned(16))) unsigned short As[16 * 32];
  __shared__ __attribute__((aligned(16))) unsigned short Bs[32 * 64];
  const int tid = threadIdx.x;
  const int m0 = blockIdx.y * 16;
  const int n0 = blockIdx.x * 64;
  const int lane = tid & 63;
  const int w = tid >> 6;
  const int mfrag = lane & 15;
  const int q = lane >> 4;
  floatx4 acc = {0.f, 0.f, 0.f, 0.f};
  for (int k0 = 0; k0 < K; k0 += 32) {
    if (tid < 64) {
      const int r = tid >> 2, cg = tid & 3;
      *(uint4*)&As[r * 32 + cg * 8] =
          *(const uint4*)(A + (size_t)(m0 + r) * K + k0 + cg * 8);
    }
    {
      const int r = tid >> 3, cg = tid & 7;
      *(uint4*)&Bs[r * 64 + cg * 8] =
          *(const uint4*)(W + (size_t)(k0 + r) * N + n0 + cg * 8);
    }
    __syncthreads();
    const short8 af = *(const short8*)&As[mfrag * 32 + q * 8];
    short8 bf;
    const int wn = w * 16 + mfrag;
#pragma unroll
    for (int j = 0; j < 8; ++j) bf[j] = (short)Bs[(q * 8 + j) * 64 + wn];
    acc = __builtin_amdgcn_mfma_f32_16x16x32_bf16(af, bf, acc, 0, 0, 0);
    __syncthreads();
  }
  const int col = n0 + w * 16 + mfrag;
  const float bv = bias[col];
#pragma unroll
  for (int i = 0; i < 4; ++i) {
    const int row = m0 + q * 4 + i;
    const int bb = row >> 7, tt = row & 127;
    out[((size_t)tt * 2048 + g * 512 + col) * 32 + bb] = f2b(acc[i] + bv);
  }
}

// ---------------------------------------------------------------------------
// init: zero partials (1 MB), Hs, flags.  grid 64 x 1024.
// ---------------------------------------------------------------------------
__global__ __launch_bounds__(1024) void init_coop(
    unsigned short* Hs, float* partials, unsigned int* flags)
{
  const int gid = blockIdx.x * 1024 + threadIdx.x;
  const float4 z = {0.f, 0.f, 0.f, 0.f};
  *(float4*)(partials + (size_t)gid * 4) = z;
  if (blockIdx.x == 0) {
    const uint4 zi = {0u, 0u, 0u, 0u};
    *(uint4*)(Hs + (size_t)threadIdx.x * 16) = zi;
    *(uint4*)(Hs + (size_t)threadIdx.x * 16 + 8) = zi;
    flags[threadIdx.x] = 0u;
  }
}

// ---------------------------------------------------------------------------
// Flag-array grid barrier (busy poll, no sleep).
// ---------------------------------------------------------------------------
__device__ __forceinline__ void flagbar(unsigned int* flags, unsigned int gen) {
  __syncthreads();
  if (threadIdx.x == 0)
    __hip_atomic_store(flags + (size_t)blockIdx.x * 32, gen,
                       __ATOMIC_RELEASE, __HIP_MEMORY_SCOPE_AGENT);
  if (threadIdx.x < NB) {
    while (__hip_atomic_load(flags + (size_t)threadIdx.x * 32,
                             __ATOMIC_RELAXED, __HIP_MEMORY_SCOPE_AGENT) < gen) {}
    __builtin_amdgcn_fence(__ATOMIC_ACQUIRE, "agent");
  }
  __syncthreads();
}

// ---------------------------------------------------------------------------
// Cooperative recurrence, wave-specialized. NB=32 blocks x 1024 threads.
// waves 0-7: attention pipeline (batch k).  waves 8-15: gate MFMA (h@U during
// attention; +cv@C after B1; acc persists in registers across syncthreads).
// ---------------------------------------------------------------------------
struct CoopParams {
  const float* Uf[4];
  const float* Cf[4];
  const float* attW1h;          // fp32 [512][256]
  unsigned short* UT;           // [NB][4][16][512] bf16
  unsigned short* CT;           // [NB][4][16][512]
  unsigned short* w1hsT;        // [NB][256][16] bf16
  unsigned short* Hs;           // [32][512] bf16 (zero-init; single buffer)
  unsigned short* CVs;          // [32][512]
  float* partials;              // [32 b][NB kb][256 a] fp32
  unsigned int* flags;          // [NB*32]
  const unsigned short* xg;     // [T][2048][32] bf16
  const unsigned short* ctxT;   // [B*L][256] bf16
  const unsigned short* cxbT;   // [B][512 d][64 l] bf16
  const float* attW2;
  const float* attB2;
  const float* mask;            // [B][T] fp32
  const int* cmask;             // [B][L]
  float* out;                   // hs|cs|ctxs fp32
};

__global__ __launch_bounds__(1024) void rnn_coop(const CoopParams p) {
  __shared__ __attribute__((aligned(16))) unsigned short h_all[32][520];
  __shared__ __attribute__((aligned(16))) unsigned short cv_all[32][520];
  __shared__ __attribute__((aligned(16))) unsigned short hloc_b[32][24];
  __shared__ float accbuf[8][16][17];
  __shared__ float pw[2][256];
  __shared__ float hw1[256];
  __shared__ float e_s[64];
  __shared__ float a_s[64];
  __shared__ float c_s[512];
  __shared__ float h_loc[512];
  __shared__ float w2s[256];

  const int k = blockIdx.x;
  const int tid = threadIdx.x;
  const int wid = tid >> 6;
  const int lane = tid & 63;
  const int q = lane >> 4, l15 = lane & 15;
  const int mw = wid - 8;            // 0..7 for MFMA waves
  const int mg = mw & 3, mh = mw >> 2;  // gate, batch-half (MFMA waves)
  const int lq = tid >> 3;           // 0..63 (attention, tid<512)
  const int kk8 = tid & 7;           // 0..7

  // ---- startup: transpose U/C fp32 -> UT/CT[k][g][n][r] bf16 ----
  {
    const int g = tid >> 8;
    const int idx = tid & 255;
    unsigned short* dU = p.UT + (size_t)k * 32768 + (size_t)g * 8192;
    unsigned short* dC = p.CT + (size_t)k * 32768 + (size_t)g * 8192;
#pragma unroll
    for (int rr = 0; rr < 2; ++rr) {
      const int r = idx * 2 + rr;
      const float* sU = p.Uf[g] + (size_t)r * 512 + k * 16;
      const float* sC = p.Cf[g] + (size_t)r * 512 + k * 16;
#pragma unroll
      for (int n = 0; n < 16; ++n) dU[(size_t)n * 512 + r] = f2b(sU[n]);
#pragma unroll
      for (int n = 0; n < 16; ++n) dC[(size_t)n * 512 + r] = f2b(sC[n]);
    }
  }
  // ---- startup: w1hsT[k][a][r16] = W1h[16k+r][a] ----
  {
    const int a = tid >> 2, r0 = (tid & 3) * 4;
    unsigned short* dst = p.w1hsT + (size_t)k * 4096 + (size_t)a * 16 + r0;
#pragma unroll
    for (int rr = 0; rr < 4; ++rr)
      dst[rr] = f2b(p.attW1h[(size_t)(k * 16 + r0 + rr) * 256 + a]);
  }
  if (tid < 256) w2s[tid] = p.attW2[tid];
  if (tid < 512) { c_s[tid] = 0.f; h_loc[tid] = 0.f; }
  const float b2v = p.attB2[0];
  const float cm_l = (tid < 512) ? (float)p.cmask[k * L_ + lq] : 0.f;
  unsigned int bgen = 0;
  __syncthreads();

  for (int t = 0; t < T_; ++t) {
    // ======== Phase A: partials+ctq loads (w0-7) | stage h_all (w8-15) ======
    uint4 ct0, ct1, ct2, ct3;
    if (tid < 512) {
      const int a = tid & 255, grp = tid >> 8;
      const float* pp = p.partials + ((size_t)k * 32 + grp * 16) * 256 + a;
      float s = 0.f;
#pragma unroll
      for (int i = 0; i < 16; ++i) s += pp[(size_t)i * 256];
      pw[grp][a] = s;
      const uint4* ct = (const uint4*)(p.ctxT + ((size_t)(k * L_ + lq)) * 256 + kk8 * 32);
      ct0 = ct[0]; ct1 = ct[1]; ct2 = ct[2]; ct3 = ct[3];
    } else {
      const int t2 = tid - 512, row = t2 >> 4, cg = t2 & 15;
      const uint4* src = (const uint4*)(p.Hs + (size_t)row * 512 + cg * 32);
      const uint4 v0 = src[0], v1 = src[1], v2 = src[2], v3 = src[3];
      *(uint4*)&h_all[row][cg * 32] = v0;
      *(uint4*)&h_all[row][cg * 32 + 8] = v1;
      *(uint4*)&h_all[row][cg * 32 + 16] = v2;
      *(uint4*)&h_all[row][cg * 32 + 24] = v3;
    }
    __syncthreads();

    // ======== Interval 1: hw1 sum | U-MFMA ks 0..5 ========
    floatx4 acc = {0.f, 0.f, 0.f, 0.f};
    const unsigned short* uB =
        p.UT + (size_t)k * 32768 + (size_t)mg * 8192 + (size_t)l15 * 512 + q * 8;
    if (wid >= 8) {
#pragma unroll
      for (int ks = 0; ks < 6; ++ks) {
        const short8 af = *(const short8*)&h_all[mh * 16 + l15][ks * 32 + q * 8];
        const short8 bf = *(const short8*)(uB + ks * 32);
        acc = __builtin_amdgcn_mfma_f32_16x16x32_bf16(af, bf, acc, 0, 0, 0);
      }
    } else if (tid < 256) {
      hw1[tid] = pw[0][tid] + pw[1][tid];
    }
    __syncthreads();

    // ======== Interval 2: scores | U-MFMA ks 6..11 ========
    if (wid >= 8) {
#pragma unroll
      for (int ks = 6; ks < 12; ++ks) {
        const short8 af = *(const short8*)&h_all[mh * 16 + l15][ks * 32 + q * 8];
        const short8 bf = *(const short8*)(uB + ks * 32);
        acc = __builtin_amdgcn_mfma_f32_16x16x32_bf16(af, bf, acc, 0, 0, 0);
      }
    } else {
      float ctv[32];
      unpack2(ct0.x, ctv[0], ctv[1]);  unpack2(ct0.y, ctv[2], ctv[3]);
      unpack2(ct0.z, ctv[4], ctv[5]);  unpack2(ct0.w, ctv[6], ctv[7]);
      unpack2(ct1.x, ctv[8], ctv[9]);  unpack2(ct1.y, ctv[10], ctv[11]);
      unpack2(ct1.z, ctv[12], ctv[13]); unpack2(ct1.w, ctv[14], ctv[15]);
      unpack2(ct2.x, ctv[16], ctv[17]); unpack2(ct2.y, ctv[18], ctv[19]);
      unpack2(ct2.z, ctv[20], ctv[21]); unpack2(ct2.w, ctv[22], ctv[23]);
      unpack2(ct3.x, ctv[24], ctv[25]); unpack2(ct3.y, ctv[26], ctv[27]);
      unpack2(ct3.z, ctv[28], ctv[29]); unpack2(ct3.w, ctv[30], ctv[31]);
      float s = 0.f;
#pragma unroll
      for (int i = 0; i < 32; ++i)
        s += tanh_fast(ctv[i] + hw1[kk8 * 32 + i]) * w2s[kk8 * 32 + i];
      s += __shfl_xor(s, 1, 8);
      s += __shfl_xor(s, 2, 8);
      s += __shfl_xor(s, 4, 8);
      if (kk8 == 0) e_s[lq] = __expf(s + b2v) * cm_l;  // raw exp, like ref
    }
    __syncthreads();

    // ======== Interval 3: softmax (w0) | U-MFMA ks 12..15 ========
    if (wid >= 8) {
#pragma unroll
      for (int ks = 12; ks < 16; ++ks) {
        const short8 af = *(const short8*)&h_all[mh * 16 + l15][ks * 32 + q * 8];
        const short8 bf = *(const short8*)(uB + ks * 32);
        acc = __builtin_amdgcn_mfma_f32_16x16x32_bf16(af, bf, acc, 0, 0, 0);
      }
    } else if (tid < 64) {
      const float e = e_s[tid];
      float s = e;
#pragma unroll
      for (int off = 1; off < 64; off <<= 1) s += __shfl_xor(s, off, 64);
      a_s[tid] = e / s;
    }
    __syncthreads();

    // ======== Interval 4: cv (vectorized cxbT) ========
    if (tid < 512) {
      const uint4* cx = (const uint4*)(p.cxbT + ((size_t)k * 512 + tid) * 64);
      float s = 0.f;
#pragma unroll
      for (int lc = 0; lc < 8; ++lc) {
        const uint4 v = cx[lc];
        float f0, f1, f2, f3, f4, f5, f6, f7;
        unpack2(v.x, f0, f1); unpack2(v.y, f2, f3);
        unpack2(v.z, f4, f5); unpack2(v.w, f6, f7);
        const int l0 = lc * 8;
        s += a_s[l0] * f0 + a_s[l0 + 1] * f1 + a_s[l0 + 2] * f2 + a_s[l0 + 3] * f3 +
             a_s[l0 + 4] * f4 + a_s[l0 + 5] * f5 + a_s[l0 + 6] * f6 + a_s[l0 + 7] * f7;
      }
      p.CVs[(size_t)k * 512 + tid] = f2b(s);
      p.out[(size_t)4194304 + ((size_t)k * T_ + t) * 512 + tid] = s;  // ctxs
    }
    flagbar(p.flags, ++bgen);  // ======== B1 ========

    // ======== stage cv_all (all) + xg prefetch (w0-7) ========
    {
      const int row = tid >> 5, cg = tid & 31;
      const uint4* src = (const uint4*)(p.CVs + (size_t)row * 512 + cg * 16);
      const uint4 v0 = src[0], v1 = src[1];
      *(uint4*)&cv_all[row][cg * 16] = v0;
      *(uint4*)&cv_all[row][cg * 16 + 8] = v1;
    }
    unsigned short xgv0 = 0, xgv1 = 0, xgv2 = 0, xgv3 = 0;
    if (tid < 512) {
      const int b = tid >> 4, j = tid & 15;
      const size_t xb = ((size_t)t * 2048 + (size_t)(k * 16 + j)) * 32 + b;
      xgv0 = p.xg[xb];
      xgv1 = p.xg[xb + (size_t)512 * 32];
      xgv2 = p.xg[xb + (size_t)1024 * 32];
      xgv3 = p.xg[xb + (size_t)1536 * 32];
    }
    __syncthreads();

    // ======== C-MFMA (w8-15): acc += cv@C ========
    if (wid >= 8) {
      const unsigned short* cB =
          p.CT + (size_t)k * 32768 + (size_t)mg * 8192 + (size_t)l15 * 512 + q * 8;
#pragma unroll
      for (int ks = 0; ks < 16; ++ks) {
        const short8 af = *(const short8*)&cv_all[mh * 16 + l15][ks * 32 + q * 8];
        const short8 bf = *(const short8*)(cB + ks * 32);
        acc = __builtin_amdgcn_mfma_f32_16x16x32_bf16(af, bf, acc, 0, 0, 0);
      }
#pragma unroll
      for (int i = 0; i < 4; ++i) accbuf[mw][q * 4 + i][l15] = acc[i];
    }
    __syncthreads();

    // ======== combiner (w0-7, tid<512) ========
    if (tid < 512) {
      const int b = tid >> 4, j = tid & 15;
      const int bh = b >> 4, br = b & 15;
      float gi_ = accbuf[bh * 4 + 0][br][j] + b2f(xgv0);
      float gf_ = accbuf[bh * 4 + 1][br][j] + b2f(xgv1);
      float gc_ = accbuf[bh * 4 + 2][br][j] + b2f(xgv2);
      float go_ = accbuf[bh * 4 + 3][br][j] + b2f(xgv3);
      const float it = sigmoid_fast(gi_);
      const float ft = sigmoid_fast(gf_);
      const float ot = sigmoid_fast(go_);
      const float c_old = c_s[tid], h_old = h_loc[tid];
      float cn = ft * c_old + it * tanh_fast(gc_);
      float hn = ot * tanh_fast(cn);
      const float mt = p.mask[(size_t)b * T_ + t];
      hn = (1.f - mt) * h_old + mt * hn;
      cn = (1.f - mt) * c_old + mt * cn;
      c_s[tid] = cn; h_loc[tid] = hn;
      const unsigned short hb = f2b(hn);
      p.Hs[(size_t)b * 512 + k * 16 + j] = hb;
      hloc_b[b][j] = hb;
      const size_t o0 = ((size_t)b * T_ + t) * 512 + k * 16 + j;
      p.out[o0] = hn;                     // hs
      p.out[(size_t)2097152 + o0] = cn;   // cs
    }
    __syncthreads();

    // ======== J: hW1 partial MFMA (w8-15) -> partials[b][k][a] ========
    if (wid >= 8) {
      const short8 z8 = {0, 0, 0, 0, 0, 0, 0, 0};
#pragma unroll
      for (int half = 0; half < 2; ++half) {
        const int acol0 = mw * 32 + half * 16;
        const unsigned short* wrow =
            p.w1hsT + (size_t)k * 4096 + (size_t)(acol0 + l15) * 16 + (q & 1) * 8;
        const short8 bfr = (q < 2) ? *(const short8*)wrow : z8;
#pragma unroll
        for (int mh2 = 0; mh2 < 2; ++mh2) {
          const short8 af = (q < 2) ? *(const short8*)&hloc_b[mh2 * 16 + l15][(q & 1) * 8] : z8;
          floatx4 pa = {0.f, 0.f, 0.f, 0.f};
          pa = __builtin_amdgcn_mfma_f32_16x16x32_bf16(af, bfr, pa, 0, 0, 0);
#pragma unroll
          for (int i = 0; i < 4; ++i)
            p.partials[((size_t)(mh2 * 16 + q * 4 + i) * 32 + k) * 256 + acol0 + l15] = pa[i];
        }
      }
    }
    flagbar(p.flags, ++bgen);  // ======== B2 ========
  }
}

// ===========================================================================
// FALLBACK: validated R5 fully-fused fp32 kernel (zero workspace).
// ===========================================================================
struct Params {
  const void* W[4]; const void* U[4]; const void* C[4]; const void* gb[4];
  const void* attW1c; const void* attW1h; const void* attB1;
  const void* attW2; const void* attB2;
  const void* mask; const void* context; const void* Xin;
  const int* cmask;
  float* out;
};

template<bool F32>
__device__ void rnn_body(const Params p) {
  __shared__ float h_s[512];
  __shared__ float x_s[512];
  __shared__ float cv_s[512];
  __shared__ float pw1[4][256];
  __shared__ float hw1[256];
  __shared__ float e_s[64];
  __shared__ float a_s[64];
  __shared__ float gpart[4][2048];
  __shared__ float cpart[2][512];

  const int b = blockIdx.x;
  const int tid = threadIdx.x;
  const int lq = tid >> 4;
  const int kk = tid & 15;
  const int part4 = tid >> 8;
  const int a256 = tid & 255;
  const int part2 = tid >> 9;
  const int d512 = tid & 511;
  const int g = a256 >> 6;
  const int j0 = a256 * 8;
  const int jj = j0 & 511;

  float ctq[16];
#pragma unroll
  for (int i = 0; i < 16; ++i) ctq[i] = 0.f;
  {
    const size_t crow = ((size_t)b * L_ + lq) * 512;
    for (int r = 0; r < 512; ++r) {
      const float cv = ld1<F32>(p.context, crow + r);
      float fa[8], fb[8];
      ld8<F32>(p.attW1c, (size_t)r * 256 + kk * 16, fa);
      ld8<F32>(p.attW1c, (size_t)r * 256 + kk * 16 + 8, fb);
#pragma unroll
      for (int i = 0; i < 8; ++i) { ctq[i] += cv * fa[i]; ctq[8 + i] += cv * fb[i]; }
    }
#pragma unroll
    for (int i = 0; i < 16; ++i) ctq[i] += ld1<F32>(p.attB1, kk * 16 + i);
  }
  float w2q[16];
#pragma unroll
  for (int i = 0; i < 16; ++i) w2q[i] = ld1<F32>(p.attW2, kk * 16 + i);
  const float b2v = ld1<F32>(p.attB2, 0);
  float bi = 0.f, bff = 0.f, bc = 0.f, bo = 0.f;
  if (tid < 512) {
    bi = ld1<F32>(p.gb[0], tid);
    bff = ld1<F32>(p.gb[1], tid);
    bc = ld1<F32>(p.gb[2], tid);
    bo = ld1<F32>(p.gb[3], tid);
  }
  float c_reg = 0.f;
  if (tid < 512) h_s[tid] = 0.f;
  __syncthreads();

  const void* Wg = p.W[g];
  const void* Ug = p.U[g];
  const void* Cg = p.C[g];
  const size_t wb = (size_t)(part4 * 128) * 512 + jj;
  const size_t w1b = (size_t)(part4 * 128) * 256 + a256;

  for (int t = 0; t < T_; ++t) {
    {
      float s = 0.f;
      const int r0 = part4 * 128;
#pragma unroll 4
      for (int r = 0; r < 128; ++r)
        s += h_s[r0 + r] * ld1<F32>(p.attW1h, w1b + (size_t)r * 256);
      pw1[part4][a256] = s;
    }
    if (tid < 512)
      x_s[tid] = ld1<F32>(p.Xin, ((size_t)b * T_ + t) * 512 + tid);
    __syncthreads();
    if (tid < 256) hw1[tid] = pw1[0][tid] + pw1[1][tid] + pw1[2][tid] + pw1[3][tid];
    __syncthreads();
    {
      float s = 0.f;
#pragma unroll
      for (int i = 0; i < 16; ++i)
        s += tanh_fast(ctq[i] + hw1[kk * 16 + i]) * w2q[i];
      s += __shfl_xor(s, 1, 16);
      s += __shfl_xor(s, 2, 16);
      s += __shfl_xor(s, 4, 16);
      s += __shfl_xor(s, 8, 16);
      if (kk == 0)
        e_s[lq] = __expf(s + b2v) * (float)p.cmask[b * L_ + lq];
    }
    __syncthreads();
    if (tid < 64) {
      const float e = e_s[tid];
      float s = e;
#pragma unroll
      for (int off = 1; off < 64; off <<= 1) s += __shfl_xor(s, off, 64);
      a_s[tid] = e / s;
    }
    __syncthreads();
    {
      const size_t cb = ((size_t)b * L_ + part2 * 32) * 512 + d512;
      float s = 0.f;
#pragma unroll 4
      for (int l = 0; l < 32; ++l)
        s += a_s[part2 * 32 + l] * ld1<F32>(p.context, cb + (size_t)l * 512);
      cpart[part2][d512] = s;
    }
    __syncthreads();
    if (tid < 512) {
      const float cv = cpart[0][tid] + cpart[1][tid];
      cv_s[tid] = cv;
      p.out[(size_t)4194304 + ((size_t)b * T_ + t) * 512 + tid] = cv;
    }
    __syncthreads();
    {
      float acc[8];
#pragma unroll
      for (int i = 0; i < 8; ++i) acc[i] = 0.f;
      const int r0 = part4 * 128;
      float f[8];
#pragma unroll 2
      for (int r = 0; r < 128; ++r) {
        const float xv = x_s[r0 + r];
        ld8<F32>(Wg, wb + (size_t)r * 512, f);
#pragma unroll
        for (int i = 0; i < 8; ++i) acc[i] += xv * f[i];
      }
#pragma unroll 2
      for (int r = 0; r < 128; ++r) {
        const float hv = h_s[r0 + r];
        ld8<F32>(Ug, wb + (size_t)r * 512, f);
#pragma unroll
        for (int i = 0; i < 8; ++i) acc[i] += hv * f[i];
      }
#pragma unroll 2
      for (int r = 0; r < 128; ++r) {
        const float cvv = cv_s[r0 + r];
        ld8<F32>(Cg, wb + (size_t)r * 512, f);
#pragma unroll
        for (int i = 0; i < 8; ++i) acc[i] += cvv * f[i];
      }
#pragma unroll
      for (int i = 0; i < 8; ++i) gpart[part4][j0 + i] = acc[i];
    }
    __syncthreads();
    if (tid < 512) {
      const int d = tid;
      float gi_ = bi + gpart[0][d] + gpart[1][d] + gpart[2][d] + gpart[3][d];
      float gf_ = bff + gpart[0][512 + d] + gpart[1][512 + d] + gpart[2][512 + d] + gpart[3][512 + d];
      float gc_ = bc + gpart[0][1024 + d] + gpart[1][1024 + d] + gpart[2][1024 + d] + gpart[3][1024 + d];
      float go_ = bo + gpart[0][1536 + d] + gpart[1][1536 + d] + gpart[2][1536 + d] + gpart[3][1536 + d];
      const float it = sigmoid_fast(gi_);
      const float ft = sigmoid_fast(gf_);
      const float ot = sigmoid_fast(go_);
      float cn = ft * c_reg + it * tanh_fast(gc_);
      float hn = ot * tanh_fast(cn);
      const float m = ld1<F32>(p.mask, (size_t)b * T_ + t);
      hn = (1.f - m) * h_s[d] + m * hn;
      cn = (1.f - m) * c_reg + m * cn;
      c_reg = cn;
      h_s[d] = hn;
      const size_t o0 = ((size_t)b * T_ + t) * 512 + d;
      p.out[o0] = hn;
      p.out[(size_t)2097152 + o0] = cn;
    }
    __syncthreads();
  }
}

__global__ __launch_bounds__(1024) void rnn_fused(const Params p) {
  const unsigned int mw = *(const unsigned int*)p.mask;
  if (mw == 0x3F800000u) rnn_body<true>(p);
  else rnn_body<false>(p);
}

// ===========================================================================
extern "C" void kernel_launch(void* const* d_in, const int* in_sizes, int n_in,
                              void* d_out, int out_size, void* d_ws, size_t ws_size,
                              hipStream_t stream) {
  (void)in_sizes; (void)n_in; (void)out_size;
  const float* X    = (const float*)d_in[0];
  const float* Ctx  = (const float*)d_in[1];
  const float* Mask = (const float*)d_in[2];
  const int*   Cm   = (const int*)d_in[3];
  const float* Wt[4] = {(const float*)d_in[4],  (const float*)d_in[8],
                        (const float*)d_in[12], (const float*)d_in[16]};
  const float* Ut[4] = {(const float*)d_in[5],  (const float*)d_in[9],
                        (const float*)d_in[13], (const float*)d_in[17]};
  const float* Ct[4] = {(const float*)d_in[6],  (const float*)d_in[10],
                        (const float*)d_in[14], (const float*)d_in[18]};
  const float* bg[4] = {(const float*)d_in[7],  (const float*)d_in[11],
                        (const float*)d_in[15], (const float*)d_in[19]};
  const float* attW1c = (const float*)d_in[20];
  const float* attW1h = (const float*)d_in[21];
  const float* attB1  = (const float*)d_in[22];
  const float* attW2  = (const float*)d_in[23];
  const float* attB2  = (const float*)d_in[24];

  // ws layout (byte offsets):
  //   xg       16,777,216 @ 0
  //   ctxT      1,048,576 @ 16,777,216
  //   Xbf       4,194,304 @ 17,825,792  (reused for cxbT after xg GEMM)
  //   cxb       2,097,152 @ 22,020,096
  //   w1cb        262,144 @ 24,117,248
  //   Wb4       2,097,152 @ 24,379,392
  //   UT        2,097,152 @ 26,476,544
  //   CT        2,097,152 @ 28,573,696
  //   w1hsT       262,144 @ 30,670,848
  //   Hs           32,768 @ 30,932,992
  //   CVs          32,768 @ 30,965,760
  //   partials  1,048,576 @ 30,998,528
  //   flags         4,096 @ 32,047,104
  const size_t WS_NEED = 32051200;  // known: ws_size >= 35,913,728 (R6-R8 ran fast path)
  if (ws_size >= WS_NEED) {
    char* ws = (char*)d_ws;
    unsigned short* xg    = (unsigned short*)(ws);
    unsigned short* ctxT  = (unsigned short*)(ws + 16777216);
    unsigned short* Xbf   = (unsigned short*)(ws + 17825792);
    unsigned short* cxbT  = (unsigned short*)(ws + 17825792);  // reuse after GEMM
    unsigned short* cxb   = (unsigned short*)(ws + 22020096);
    unsigned short* w1cb  = (unsigned short*)(ws + 24117248);
    unsigned short* Wb4   = (unsigned short*)(ws + 24379392);
    unsigned short* UT    = (unsigned short*)(ws + 26476544);
    unsigned short* CT    = (unsigned short*)(ws + 28573696);
    unsigned short* w1hsT = (unsigned short*)(ws + 30670848);
    unsigned short* Hs    = (unsigned short*)(ws + 30932992);
    unsigned short* CVs   = (unsigned short*)(ws + 30965760);
    float*          parts = (float*)(ws + 30998528);
    unsigned int*   flags = (unsigned int*)(ws + 32047104);

    conv_all<<<dim3(4224), dim3(256), 0, stream>>>(
        X, Ctx, attW1c, Wt[0], Wt[1], Wt[2], Wt[3], Xbf, cxb, w1cb, Wb4);
    GB4 gb4 = {bg[0], bg[1], bg[2], bg[3]};
    gemm_xg<<<dim3(8, 256, 4), dim3(256), 0, stream>>>(Xbf, Wb4, gb4, xg);
    gemm_bias<<<dim3(4, 128), dim3(256), 0, stream>>>(
        cxb, w1cb, attB1, ctxT, 2048, 256, 256, 0);
    transpose_cxbT<<<dim3(32, 8), dim3(256), 0, stream>>>(Ctx, cxbT);
    init_coop<<<dim3(64), dim3(1024), 0, stream>>>(Hs, parts, flags);

    CoopParams cp;
    for (int g = 0; g < 4; ++g) { cp.Uf[g] = Ut[g]; cp.Cf[g] = Ct[g]; }
    cp.attW1h = attW1h;
    cp.UT = UT; cp.CT = CT; cp.w1hsT = w1hsT;
    cp.Hs = Hs; cp.CVs = CVs;
    cp.partials = parts; cp.flags = flags;
    cp.xg = xg; cp.ctxT = ctxT; cp.cxbT = cxbT;
    cp.attW2 = attW2; cp.attB2 = attB2; cp.mask = Mask; cp.cmask = Cm;
    cp.out = (float*)d_out;
    rnn_coop<<<dim3(NB), dim3(1024), 0, stream>>>(cp);
  } else {
    Params p;
    p.Xin = X; p.context = Ctx; p.mask = Mask; p.cmask = Cm;
    for (int g = 0; g < 4; ++g) {
      p.W[g] = Wt[g]; p.U[g] = Ut[g]; p.C[g] = Ct[g]; p.gb[g] = bg[g];
    }
    p.attW1c = attW1c; p.attW1h = attW1h; p.attB1 = attB1;
    p.attW2 = attW2; p.attB2 = attB2;
    p.out = (float*)d_out;
    rnn_fused<<<dim3(32), dim3(1024), 0, stream>>>(p);
  }
}